// Round 6
// baseline (109.673 us; speedup 1.0000x reference)
//
#include <hip/hip_runtime.h>
#include <math.h>

using short8   = __attribute__((ext_vector_type(8))) short;
using floatx4  = __attribute__((ext_vector_type(4))) float;
using ushort4v = __attribute__((ext_vector_type(4))) unsigned short;

#define GLD16(gsrc, ldst) __builtin_amdgcn_global_load_lds( \
    (const __attribute__((address_space(1))) void*)(gsrc),  \
    (__attribute__((address_space(3))) void*)(ldst), 16, 0, 0)

__device__ __forceinline__ unsigned short f2bf(float x) {
  union { float f; unsigned u; } v; v.f = x;
  unsigned r = (v.u + 0x7FFFu + ((v.u >> 16) & 1u)) >> 16;
  return (unsigned short)r;
}
__device__ __forceinline__ float bf2f(unsigned short u) {
  union { unsigned u; float f; } v; v.u = ((unsigned)u) << 16;
  return v.f;
}
__device__ __forceinline__ short8 pack_a(int4 v0, int4 v1) {
  union { uint4 u; short8 s; } r;
  r.u.x = ((unsigned)v0.x | ((unsigned)v0.y << 16)) * 0x3F80u;
  r.u.y = ((unsigned)v0.z | ((unsigned)v0.w << 16)) * 0x3F80u;
  r.u.z = ((unsigned)v1.x | ((unsigned)v1.y << 16)) * 0x3F80u;
  r.u.w = ((unsigned)v1.z | ((unsigned)v1.w << 16)) * 0x3F80u;
  return r.s;
}

// ---------------- K1: Wh = h @ W  (f32 vector GEMM, bf16 output) ----------------
__global__ __launch_bounds__(256) void wh_gemm(
    const float* __restrict__ h, const float* __restrict__ W,
    unsigned short* __restrict__ Whb) {
  __shared__ __align__(16) float Al[16][64];
  __shared__ __align__(16) float Bl[16][128];
  const int m0 = blockIdx.x * 64;
  const int n0 = blockIdx.y * 128;
  const int t  = threadIdx.x;
  const int tx = t & 15, ty = t >> 4;
  float acc[4][8];
#pragma unroll
  for (int i = 0; i < 4; ++i)
#pragma unroll
    for (int j = 0; j < 8; ++j) acc[i][j] = 0.0f;

  for (int k0 = 0; k0 < 256; k0 += 16) {
    {
      int m = t & 63, kq = t >> 6;
      float4 v = *(const float4*)&h[(size_t)(m0 + m) * 256 + k0 + kq * 4];
      Al[kq * 4 + 0][m] = v.x; Al[kq * 4 + 1][m] = v.y;
      Al[kq * 4 + 2][m] = v.z; Al[kq * 4 + 3][m] = v.w;
    }
    {
      int n4 = t & 31, kr = t >> 5;
      *(float4*)&Bl[kr][n4 * 4]     = *(const float4*)&W[(size_t)(k0 + kr) * 256 + n0 + n4 * 4];
      *(float4*)&Bl[kr + 8][n4 * 4] = *(const float4*)&W[(size_t)(k0 + kr + 8) * 256 + n0 + n4 * 4];
    }
    __syncthreads();
#pragma unroll
    for (int k = 0; k < 16; ++k) {
      float4 av = *(const float4*)&Al[k][ty * 4];
      float4 b0 = *(const float4*)&Bl[k][tx * 4];
      float4 b1 = *(const float4*)&Bl[k][64 + tx * 4];
      float aa[4] = {av.x, av.y, av.z, av.w};
      float bb[8] = {b0.x, b0.y, b0.z, b0.w, b1.x, b1.y, b1.z, b1.w};
#pragma unroll
      for (int i = 0; i < 4; ++i)
#pragma unroll
        for (int j = 0; j < 8; ++j) acc[i][j] = fmaf(aa[i], bb[j], acc[i][j]);
    }
    __syncthreads();
  }
#pragma unroll
  for (int i = 0; i < 4; ++i) {
    size_t row = (size_t)(m0 + ty * 4 + i);
    ushort4v o0, o1;
#pragma unroll
    for (int j = 0; j < 4; ++j) { o0[j] = f2bf(acc[i][j]); o1[j] = f2bf(acc[i][4 + j]); }
    *(ushort4v*)&Whb[row * 256 + n0 + tx * 4]      = o0;
    *(ushort4v*)&Whb[row * 256 + n0 + 64 + tx * 4] = o1;
  }
}

// ---------------- K2a: g[row] = Wh[row,:] . a2 ----------------
__global__ __launch_bounds__(256) void g_rows(
    const unsigned short* __restrict__ Whb, const float* __restrict__ a,
    float* __restrict__ g) {
  int row = blockIdx.x * 4 + (threadIdx.x >> 6);
  int L = threadIdx.x & 63;
  ushort4v wv = *(const ushort4v*)&Whb[(size_t)row * 256 + L * 4];
  float4 av = *(const float4*)&a[256 + L * 4];
  float d = bf2f(wv[0]) * av.x + bf2f(wv[1]) * av.y + bf2f(wv[2]) * av.z + bf2f(wv[3]) * av.w;
#pragma unroll
  for (int off = 32; off > 0; off >>= 1) d += __shfl_xor(d, off);
  if (L == 0) g[row] = d;
}

// ---------------- K2b: per-batch max of g ----------------
__global__ __launch_bounds__(256) void batch_max(
    const float* __restrict__ g, float* __restrict__ Mb) {
  __shared__ float red[4];
  int b = blockIdx.x, t = threadIdx.x;
  float m = -1e30f;
  for (int i = t; i < 2048; i += 256) m = fmaxf(m, g[(size_t)b * 2048 + i]);
#pragma unroll
  for (int off = 32; off > 0; off >>= 1) m = fmaxf(m, __shfl_xor(m, off));
  if ((t & 63) == 0) red[t >> 6] = m;
  __syncthreads();
  if (t == 0) Mb[b] = fmaxf(fmaxf(red[0], red[1]), fmaxf(red[2], red[3]));
}

// ---------------- K2c: tile-contiguous B (unswizzled slots):
// Bt[((b*64 + kt)*320 + c)*64B], 64B = k-slots 0..3 (8 bf16 each) of s_j*Wh[b,j,c]
// (c==256 -> s_j; 257..319 -> 0)
__global__ __launch_bounds__(256) void build_bt(
    const unsigned short* __restrict__ Whb, const float* __restrict__ g,
    const float* __restrict__ Mb, unsigned short* __restrict__ Bt) {
  __shared__ __align__(16) unsigned short tile[320 * 64];  // [c][j]
  const int blk = blockIdx.x;
  const int b   = blk >> 5;
  const int j0  = (blk & 31) * 64;
  const int kt_base = (blk & 31) * 2;
  const int t   = threadIdx.x;
  const int j   = t & 63;
  const int q0  = t >> 6;
  const int row = b * 2048 + j0 + j;
  const float s = expf(g[row] - Mb[b]);
  for (int q = q0; q < 64; q += 4) {
    ushort4v wv = *(const ushort4v*)&Whb[(size_t)row * 256 + q * 4];
    int c = q * 4;
    tile[(c + 0) * 64 + j] = f2bf(s * bf2f(wv[0]));
    tile[(c + 1) * 64 + j] = f2bf(s * bf2f(wv[1]));
    tile[(c + 2) * 64 + j] = f2bf(s * bf2f(wv[2]));
    tile[(c + 3) * 64 + j] = f2bf(s * bf2f(wv[3]));
  }
  if (q0 == 0) tile[256 * 64 + j] = f2bf(s);
  for (int z = t; z < 63 * 64; z += 256) tile[257 * 64 + z] = 0;
  __syncthreads();
#pragma unroll
  for (int p = 0; p < 10; ++p) {
    int id = t + 256 * p;          // 0..2559 -> (c, off)
    int c = id >> 3, off = id & 7;
    int kt_l = off >> 2, slot = off & 3;
    size_t dst = ((size_t)((b * 64 + kt_base + kt_l) * 320 + c)) * 64 + (slot << 4);
    *(int4*)((char*)Bt + dst) = *(const int4*)&tile[c * 64 + off * 8];
  }
}

// ---------------- K3: [num|den] = adj @ Bt^T ----------------
// grid 512 (b=bid&7 XCD-pinned, 2 blocks/CU). BM=32, BN=320, BK=32, 4 waves.
// A via gld_lds (4 x 4KB buffers, swizzled, 2x reuse); B direct global->reg
// (4 named sets, coalesced 1KB/instr from L2-resident Bt). Prefetch depth 3,
// per-wave 6 vm-ops/tile, gate s_waitcnt vmcnt(12) (tail: 12,12,6,0).
__global__ __launch_bounds__(256, 2) void gat_main(
    const int* __restrict__ adj, const unsigned short* __restrict__ Bt,
    float* __restrict__ out) {
  __shared__ __align__(16) char lds[16512];  // 4 x 4KB A bufs + 128B den
  const int bid = blockIdx.x;
  const int b   = bid & 7;
  const int rb  = bid >> 3;
  const int i0  = rb * 32;
  const int tid = threadIdx.x;
  const int w   = tid >> 6, L = tid & 63;
  const int fr  = L & 15, kc = L >> 4;

  const char* adjB = (const char*)adj + ((size_t)b * 2048 + i0) * 8192;
  // A staging source: wave w rows w*8..+7, slot pre-swizzled ^(row&7)
  const char* asrc = adjB + (size_t)(w * 8 + (L >> 3)) * 8192 + (((L & 7) ^ (L >> 3)) << 4);
  // B per-lane direct source: col = w*80 + nf*16 + fr, slot kc
  const char* bsrc = (const char*)Bt + (size_t)b * 1310720
                   + (size_t)(w * 80 + fr) * 64 + (kc << 4);

  char* buf0 = lds;
  char* buf1 = lds + 4096;
  char* buf2 = lds + 8192;
  char* buf3 = lds + 12288;

  floatx4 acc[2][5];
#pragma unroll
  for (int i = 0; i < 2; ++i)
#pragma unroll
    for (int n = 0; n < 5; ++n) acc[i][n] = (floatx4)0.0f;

  short8 pb0[5], pb1[5], pb2[5], pb3[5];

#define STAGEA(TT, BASE) { GLD16(asrc + (size_t)(TT) * 128, (BASE) + w * 1024); }

#define LOADB(TT, SET) {                                  \
    const char* p_ = bsrc + (size_t)(TT) * 20480;         \
    SET[0] = *(const short8*)(p_);                        \
    SET[1] = *(const short8*)(p_ + 1024);                 \
    SET[2] = *(const short8*)(p_ + 2048);                 \
    SET[3] = *(const short8*)(p_ + 3072);                 \
    SET[4] = *(const short8*)(p_ + 4096);                 \
  }

#define COMPUTE(BASE, SET) {                                                     \
    short8 af_[2];                                                               \
    _Pragma("unroll")                                                            \
    for (int mf = 0; mf < 2; ++mf) {                                             \
      const char* ar_ = (BASE) + (mf * 16 + fr) * 128;                           \
      int4 a0_ = *(const int4*)(ar_ + (((2 * kc)     ^ (fr & 7)) << 4));         \
      int4 a1_ = *(const int4*)(ar_ + (((2 * kc + 1) ^ (fr & 7)) << 4));         \
      af_[mf] = pack_a(a0_, a1_);                                                \
    }                                                                            \
    _Pragma("unroll")                                                            \
    for (int nf = 0; nf < 5; ++nf) {                                             \
      acc[0][nf] = __builtin_amdgcn_mfma_f32_16x16x32_bf16(af_[0], SET[nf], acc[0][nf], 0, 0, 0); \
      acc[1][nf] = __builtin_amdgcn_mfma_f32_16x16x32_bf16(af_[1], SET[nf], acc[1][nf], 0, 0, 0); \
    }                                                                            \
  }

#define PH(GATE, CBUF, CSET, STT, SBUF, SSET) {            \
    asm volatile("s_waitcnt vmcnt(" #GATE ")" ::: "memory"); \
    __builtin_amdgcn_s_barrier();                          \
    STAGEA(STT, SBUF);                                     \
    LOADB(STT, SSET);                                      \
    COMPUTE(CBUF, CSET);                                   \
  }

#define PHN(GATE, CBUF, CSET) {                            \
    asm volatile("s_waitcnt vmcnt(" #GATE ")" ::: "memory"); \
    __builtin_amdgcn_s_barrier();                          \
    COMPUTE(CBUF, CSET);                                   \
  }

  STAGEA(0, buf0); LOADB(0, pb0);
  STAGEA(1, buf1); LOADB(1, pb1);
  STAGEA(2, buf2); LOADB(2, pb2);

#pragma unroll 1
  for (int k = 0; k < 15; ++k) {
    int t4 = k * 4;
    PH(12, buf0, pb0, t4 + 3, buf3, pb3);
    PH(12, buf1, pb1, t4 + 4, buf0, pb0);
    PH(12, buf2, pb2, t4 + 5, buf1, pb1);
    PH(12, buf3, pb3, t4 + 6, buf2, pb2);
  }
  // t = 60..63
  PH (12, buf0, pb0, 63, buf3, pb3);
  PHN(12, buf1, pb1);
  PHN(6,  buf2, pb2);
  PHN(0,  buf3, pb3);

  // epilogue: den = col 256 -> wave 3, nf==1, fr==0
  float* denL = (float*)(lds + 16384);
  const int q = L >> 4;
  if (w == 3 && fr == 0) {
#pragma unroll
    for (int mf = 0; mf < 2; ++mf)
#pragma unroll
      for (int jj = 0; jj < 4; ++jj)
        denL[mf * 16 + q * 4 + jj] = acc[mf][1][jj];
  }
  __syncthreads();
  float invd[2][4];
#pragma unroll
  for (int mf = 0; mf < 2; ++mf)
#pragma unroll
    for (int jj = 0; jj < 4; ++jj)
      invd[mf][jj] = 1.0f / denL[mf * 16 + q * 4 + jj];
#pragma unroll
  for (int mf = 0; mf < 2; ++mf) {
#pragma unroll
    for (int nf = 0; nf < 5; ++nf) {
      int col = w * 80 + nf * 16 + fr;
      if (col < 256) {
#pragma unroll
        for (int jj = 0; jj < 4; ++jj) {
          int row = mf * 16 + q * 4 + jj;
          float v = acc[mf][nf][jj] * invd[mf][jj];
          v = (v > 0.0f) ? v : expm1f(v);
          out[((size_t)b * 2048 + i0 + row) * 256 + col] = v;
        }
      }
    }
  }
#undef PH
#undef PHN
#undef COMPUTE
#undef LOADB
#undef STAGEA
}

extern "C" void kernel_launch(void* const* d_in, const int* in_sizes, int n_in,
                              void* d_out, int out_size, void* d_ws, size_t ws_size,
                              hipStream_t stream) {
  const float* h   = (const float*)d_in[0];
  const int*   adj = (const int*)d_in[1];
  const float* W   = (const float*)d_in[2];
  const float* a   = (const float*)d_in[3];
  float* out = (float*)d_out;

  char* ws = (char*)d_ws;
  if (ws_size < 18940160) return;
  unsigned short* Whb = (unsigned short*)ws;             // 8,388,608 B
  float* g            = (float*)(ws + 8388608);          //    65,536 B
  float* Mb           = (float*)(ws + 8454144);          //       256 B
  unsigned short* Bt  = (unsigned short*)(ws + 8454400); // 10,485,760 B

  wh_gemm  <<<dim3(256, 2), 256, 0, stream>>>(h, W, Whb);
  g_rows   <<<4096,        256, 0, stream>>>(Whb, a, g);
  batch_max<<<8,           256, 0, stream>>>(g, Mb);
  build_bt <<<256,         256, 0, stream>>>(Whb, g, Mb, Bt);
  gat_main <<<512,         256, 0, stream>>>(adj, Bt, out);
}